// Round 14
// baseline (196.438 us; speedup 1.0000x reference)
//
#include <hip/hip_runtime.h>
#include <hip/hip_bf16.h>
#include <math.h>

#define B_   256
#define D1_  512
#define T_   256
#define O1_  256
#define O2_  128
#define OT   64

typedef __attribute__((ext_vector_type(8))) _Float16 f16x8;
typedef __attribute__((ext_vector_type(4))) float f32x4;

#define MFMAH __builtin_amdgcn_mfma_f32_16x16x32_f16

// ws layout: xT fp16 [b][t][d], WT fp16 [s][t], W2T fp16 [s2][t], W1h fp16 [o][d]
#define XT_BYTES  (B_ * T_ * D1_ * 2u)    // 67,108,864
#define WT_BYTES  (T_ * T_ * 2u)          // 131,072
#define W2T_BYTES (T_ * O2_ * 2u)         // 65,536
#define W1H_BYTES (O1_ * D1_ * 2u)        // 262,144
#define WS_NEED   ((size_t)XT_BYTES + WT_BYTES + W2T_BYTES + W1H_BYTES)

__device__ inline f16x8 ldb128(const char* p) { return *(const f16x8*)p; }

// ===== prep: WT[s][t]=fp16(W[t][s]); W2T[s2][t]=fp16(W2[t][s2]); W1h=fp16(W1) =====
__global__ __launch_bounds__(256) void prep_weights(
    const float* __restrict__ W, const float* __restrict__ W2,
    const float* __restrict__ W1, _Float16* __restrict__ WT,
    _Float16* __restrict__ W2T, _Float16* __restrict__ W1h)
{
    int g = blockIdx.x * 256 + threadIdx.x;
    if (g < T_ * T_) {
        int s = g >> 8, t = g & 255;
        WT[g] = (_Float16)W[t * T_ + s];
    } else if (g < T_ * T_ + T_ * O2_) {
        int h = g - T_ * T_;
        int s2 = h >> 8, t = h & 255;
        W2T[h] = (_Float16)W2[t * O2_ + s2];
    } else {
        int h = g - (T_ * T_ + T_ * O2_);
        if (h < O1_ * D1_) W1h[h] = (_Float16)W1[h];
    }
}

// ===== transpose x: xT[b][t][d] = fp16(x[b][d][t]) — 64x64 LDS tiles =====
__global__ __launch_bounds__(256) void transpose_x(
    const float* __restrict__ x, _Float16* __restrict__ xT)
{
    __shared__ float tile[64][65];
    const int bid = blockIdx.x;
    const int b   = bid >> 5;
    const int rem = bid & 31;
    const int d0  = (rem >> 2) * 64;
    const int t0  = (rem & 3) * 64;
    const int tid = threadIdx.x;

    { // read phase: coalesced along t
        const int j  = tid & 15;     // t-quad
        const int r0 = tid >> 4;     // 0..15
        #pragma unroll
        for (int rr = 0; rr < 4; ++rr) {
            int dl = r0 + rr * 16;
            float4 v = *(const float4*)(x + ((size_t)b * D1_ + d0 + dl) * T_ + t0 + j * 4);
            tile[j * 4 + 0][dl] = v.x;
            tile[j * 4 + 1][dl] = v.y;
            tile[j * 4 + 2][dl] = v.z;
            tile[j * 4 + 3][dl] = v.w;
        }
    }
    __syncthreads();
    { // write phase: coalesced along d, fp16
        const int trow = tid >> 2;         // 0..63
        const int seg  = (tid & 3) * 16;   // 16 d each
        _Float16 h[16];
        #pragma unroll
        for (int k = 0; k < 16; ++k) h[k] = (_Float16)tile[trow][seg + k];
        uint4* dst = (uint4*)(xT + ((size_t)b * T_ + t0 + trow) * D1_ + d0 + seg);
        dst[0] = ((uint4*)h)[0];
        dst[1] = ((uint4*)h)[1];
    }
}

// ===== fused: E = W1h@xT -> S = E@WT -> softmax/blend -> Y = blended@W2T =====
// OT=64 o-rows, 512 threads (8 waves 2m x 4n). LDS = 34.3 KB. All B/A operands
// are single contiguous 16-B fp16 loads (pre-transposed), reg-prefetched 1
// chunk ahead. NO barriers in the GEMM loops — waves decouple, TLP hides
// latency. 3 barriers total (E publish, softmax reduce, blend publish).
__global__ __launch_bounds__(512) void tabl_mfma(
    const _Float16* __restrict__ xT, const _Float16* __restrict__ W1h,
    const _Float16* __restrict__ WT, const _Float16* __restrict__ W2T,
    const float* __restrict__ alpha, const float* __restrict__ bias,
    float* __restrict__ out)
{
    __shared__ __align__(16) char Eh[OT * 512];   // E / blended (fp16, XOR-swizzled)
    __shared__ float redm[4][OT];
    __shared__ float reds[4][OT];

    const int tid    = threadIdx.x;
    const int lane16 = tid & 15;
    const int lg     = (tid >> 4) & 3;
    const int wid    = tid >> 6;        // 0..7
    const int wm     = wid >> 2;        // 0..1
    const int wn     = wid & 3;         // 0..3

    // XCD swizzle: the 4 o-tiles of a batch land on the same XCD.
    const int bid = blockIdx.x;
    const int idx = bid >> 3;
    const int b     = (bid & 7) + 8 * (idx >> 2);
    const int obase = (idx & 3) * OT;

    const int eR[2]    = { wm * 32 + lane16, wm * 32 + 16 + lane16 };
    const int eBase[2] = { eR[0] * 512, eR[1] * 512 };
    const int eSw[2]   = { (eR[0] & 7) << 4, (eR[1] & 7) << 4 };

    // ================= Stage 1: E = W1h @ xh (no barriers) =================
    f32x4 Eacc[2][4];
    #pragma unroll
    for (int mt = 0; mt < 2; ++mt)
        #pragma unroll
        for (int nt = 0; nt < 4; ++nt) Eacc[mt][nt] = (f32x4){0.f,0.f,0.f,0.f};

    const _Float16* xTb = xT + (size_t)b * T_ * D1_;
    const _Float16* aB[2] = {
        W1h + (size_t)(obase + eR[0]) * D1_ + lg * 8,
        W1h + (size_t)(obase + eR[1]) * D1_ + lg * 8 };
    const _Float16* bB[4];
    #pragma unroll
    for (int nt = 0; nt < 4; ++nt)
        bB[nt] = xTb + (size_t)(wn * 64 + nt * 16 + lane16) * D1_ + lg * 8;

    f16x8 Bpf[4], Apf[2];
    #pragma unroll
    for (int nt = 0; nt < 4; ++nt) Bpf[nt] = *(const f16x8*)bB[nt];
    Apf[0] = *(const f16x8*)aB[0];
    Apf[1] = *(const f16x8*)aB[1];

    #pragma unroll 2
    for (int c = 0; c < 16; ++c) {
        f16x8 Bc[4], Ac[2];
        #pragma unroll
        for (int nt = 0; nt < 4; ++nt) Bc[nt] = Bpf[nt];
        Ac[0] = Apf[0]; Ac[1] = Apf[1];
        if (c < 15) {
            #pragma unroll
            for (int nt = 0; nt < 4; ++nt)
                Bpf[nt] = *(const f16x8*)(bB[nt] + (c + 1) * 32);
            Apf[0] = *(const f16x8*)(aB[0] + (c + 1) * 32);
            Apf[1] = *(const f16x8*)(aB[1] + (c + 1) * 32);
        }
        __builtin_amdgcn_s_setprio(1);
        #pragma unroll
        for (int nt = 0; nt < 4; ++nt)
            #pragma unroll
            for (int mt = 0; mt < 2; ++mt)
                Eacc[mt][nt] = MFMAH(Ac[mt], Bc[nt], Eacc[mt][nt], 0,0,0);
        __builtin_amdgcn_s_setprio(0);
    }

    // stage-2 B prologue (issue before publish barrier to hide)
    const _Float16* wB[4];
    #pragma unroll
    for (int nt = 0; nt < 4; ++nt)
        wB[nt] = WT + (size_t)(wn * 64 + nt * 16 + lane16) * T_ + lg * 8;
    f16x8 Wpf[4];
    #pragma unroll
    for (int nt = 0; nt < 4; ++nt) Wpf[nt] = *(const f16x8*)wB[nt];

    // publish E (fp16, XOR-swizzled); Eacc dies here
    #pragma unroll
    for (int mt = 0; mt < 2; ++mt)
        #pragma unroll
        for (int nt = 0; nt < 4; ++nt)
            #pragma unroll
            for (int i = 0; i < 4; ++i) {
                int r = wm * 32 + mt * 16 + lg * 4 + i;
                int t = wn * 64 + nt * 16 + lane16;
                union { _Float16 h; unsigned short u; } cc;
                cc.h = (_Float16)Eacc[mt][nt][i];
                *(unsigned short*)(Eh + r * 512 + ((2 * t) ^ ((r & 7) << 4))) = cc.u;
            }
    __syncthreads();   // barrier 1

    // ================= Stage 2: S = Eh @ WT (no barriers) =================
    f32x4 Sacc[2][4];
    #pragma unroll
    for (int mt = 0; mt < 2; ++mt)
        #pragma unroll
        for (int nt = 0; nt < 4; ++nt) Sacc[mt][nt] = (f32x4){0.f,0.f,0.f,0.f};

    #pragma unroll 2
    for (int c = 0; c < 8; ++c) {
        f16x8 Af[2];
        #pragma unroll
        for (int mt = 0; mt < 2; ++mt)
            Af[mt] = ldb128(Eh + eBase[mt] + ((c * 64 + lg * 16) ^ eSw[mt]));
        f16x8 Bc[4];
        #pragma unroll
        for (int nt = 0; nt < 4; ++nt) Bc[nt] = Wpf[nt];
        if (c < 7) {
            #pragma unroll
            for (int nt = 0; nt < 4; ++nt)
                Wpf[nt] = *(const f16x8*)(wB[nt] + (c + 1) * 32);
        }
        __builtin_amdgcn_s_setprio(1);
        #pragma unroll
        for (int nt = 0; nt < 4; ++nt)
            #pragma unroll
            for (int mt = 0; mt < 2; ++mt)
                Sacc[mt][nt] = MFMAH(Af[mt], Bc[nt], Sacc[mt][nt], 0,0,0);
        __builtin_amdgcn_s_setprio(0);
    }

    // ============ row softmax over s (4 wn groups) + blend (Eh in place) ============
    const float a_ = alpha[0];
    float pm[2][4];
    #pragma unroll
    for (int mt = 0; mt < 2; ++mt)
        #pragma unroll
        for (int i = 0; i < 4; ++i) {
            float m = fmaxf(fmaxf(Sacc[mt][0][i], Sacc[mt][1][i]),
                            fmaxf(Sacc[mt][2][i], Sacc[mt][3][i]));
            m = fmaxf(m, __shfl_xor(m, 1));
            m = fmaxf(m, __shfl_xor(m, 2));
            m = fmaxf(m, __shfl_xor(m, 4));
            m = fmaxf(m, __shfl_xor(m, 8));
            float s = 0.f;
            #pragma unroll
            for (int nt = 0; nt < 4; ++nt) {
                float p = __expf(Sacc[mt][nt][i] - m);
                Sacc[mt][nt][i] = p; s += p;
            }
            s += __shfl_xor(s, 1);
            s += __shfl_xor(s, 2);
            s += __shfl_xor(s, 4);
            s += __shfl_xor(s, 8);
            pm[mt][i] = m;
            if (lane16 == 0) {
                int r = wm * 32 + mt * 16 + lg * 4 + i;
                redm[wn][r] = m; reds[wn][r] = s;
            }
        }
    __syncthreads();   // barrier 2 (redm ready; all stage-2 Eh reads done)

    #pragma unroll
    for (int mt = 0; mt < 2; ++mt)
        #pragma unroll
        for (int i = 0; i < 4; ++i) {
            int r = wm * 32 + mt * 16 + lg * 4 + i;
            float M = fmaxf(fmaxf(redm[0][r], redm[1][r]),
                            fmaxf(redm[2][r], redm[3][r]));
            float den = reds[0][r] * __expf(redm[0][r] - M)
                      + reds[1][r] * __expf(redm[1][r] - M)
                      + reds[2][r] * __expf(redm[2][r] - M)
                      + reds[3][r] * __expf(redm[3][r] - M);
            float sc = __expf(pm[mt][i] - M) / den;
            #pragma unroll
            for (int nt = 0; nt < 4; ++nt) {
                float f = a_ + (1.f - a_) * Sacc[mt][nt][i] * sc;
                int t = wn * 64 + nt * 16 + lane16;
                int off = r * 512 + ((2 * t) ^ ((r & 7) << 4));
                union { _Float16 h; unsigned short u; } cc;
                cc.u = *(const unsigned short*)(Eh + off);
                cc.h = (_Float16)((float)cc.h * f);
                *(unsigned short*)(Eh + off) = cc.u;
            }
        }
    // stage-3 B prologue (hide under barrier)
    const _Float16* zB[2] = {
        W2T + (size_t)(wn * 32 + lane16) * T_ + lg * 8,
        W2T + (size_t)(wn * 32 + 16 + lane16) * T_ + lg * 8 };
    f16x8 Zpf[2];
    Zpf[0] = *(const f16x8*)zB[0];
    Zpf[1] = *(const f16x8*)zB[1];
    __syncthreads();   // barrier 3 (blend visible)

    // ========== Stage 3: Y = blended @ W2T + bias (no barriers) ==========
    f32x4 Yacc[2][2];
    #pragma unroll
    for (int mt = 0; mt < 2; ++mt)
        #pragma unroll
        for (int nt = 0; nt < 2; ++nt) Yacc[mt][nt] = (f32x4){0.f,0.f,0.f,0.f};

    #pragma unroll 2
    for (int c = 0; c < 8; ++c) {
        f16x8 Af[2];
        #pragma unroll
        for (int mt = 0; mt < 2; ++mt)
            Af[mt] = ldb128(Eh + eBase[mt] + ((c * 64 + lg * 16) ^ eSw[mt]));
        f16x8 Bc[2] = { Zpf[0], Zpf[1] };
        if (c < 7) {
            Zpf[0] = *(const f16x8*)(zB[0] + (c + 1) * 32);
            Zpf[1] = *(const f16x8*)(zB[1] + (c + 1) * 32);
        }
        __builtin_amdgcn_s_setprio(1);
        #pragma unroll
        for (int nt = 0; nt < 2; ++nt)
            #pragma unroll
            for (int mt = 0; mt < 2; ++mt)
                Yacc[mt][nt] = MFMAH(Af[mt], Bc[nt], Yacc[mt][nt], 0,0,0);
        __builtin_amdgcn_s_setprio(0);
    }

    // epilogue: + bias, store pre-softmax Y
    #pragma unroll
    for (int mt = 0; mt < 2; ++mt)
        #pragma unroll
        for (int nt = 0; nt < 2; ++nt)
            #pragma unroll
            for (int i = 0; i < 4; ++i) {
                int o  = obase + wm * 32 + mt * 16 + lg * 4 + i;
                int s2 = wn * 32 + nt * 16 + lane16;
                out[((size_t)b * O1_ + o) * O2_ + s2] =
                    Yacc[mt][nt][i] + bias[(size_t)o * O2_ + s2];
            }
}

// in-place softmax over axis 1 (O1); one block per batch
__global__ __launch_bounds__(256) void softmax_o1(float* __restrict__ out)
{
    __shared__ float sm[2][128], ss[2][128];
    const int b  = blockIdx.x;
    const int s2 = threadIdx.x & 127;
    const int oh = threadIdx.x >> 7;
    float* p = out + (size_t)b * (O1_ * O2_) + s2;
    float m = -INFINITY, s = 0.f;
    #pragma unroll 4
    for (int o = oh * 128; o < oh * 128 + 128; ++o) {
        float v = p[(size_t)o * O2_];
        float mn = fmaxf(m, v);
        s = s * __expf(m - mn) + __expf(v - mn);
        m = mn;
    }
    sm[oh][s2] = m; ss[oh][s2] = s;
    __syncthreads();
    float M = fmaxf(sm[0][s2], sm[1][s2]);
    float S = ss[0][s2] * __expf(sm[0][s2] - M) + ss[1][s2] * __expf(sm[1][s2] - M);
    float inv = 1.f / S;
    #pragma unroll 4
    for (int o = oh * 128; o < oh * 128 + 128; ++o) {
        float v = p[(size_t)o * O2_];
        p[(size_t)o * O2_] = __expf(v - M) * inv;
    }
}

extern "C" void kernel_launch(void* const* d_in, const int* in_sizes, int n_in,
                              void* d_out, int out_size, void* d_ws, size_t ws_size,
                              hipStream_t stream)
{
    const float* x     = (const float*)d_in[0];
    const float* W1    = (const float*)d_in[1];
    const float* W     = (const float*)d_in[2];
    const float* W2    = (const float*)d_in[3];
    const float* alpha = (const float*)d_in[4];
    const float* bias  = (const float*)d_in[5];
    float* out = (float*)d_out;

    if (ws_size < WS_NEED) return;   // scratch too small -> clean failure signal

    char* ws = (char*)d_ws;
    _Float16* xT  = (_Float16*)ws;
    _Float16* WT  = (_Float16*)(ws + XT_BYTES);
    _Float16* W2T = (_Float16*)(ws + XT_BYTES + WT_BYTES);
    _Float16* W1h = (_Float16*)(ws + XT_BYTES + WT_BYTES + W2T_BYTES);

    prep_weights<<<dim3(896), 256, 0, stream>>>(W, W2, W1, WT, W2T, W1h);
    transpose_x<<<dim3(8192), 256, 0, stream>>>(x, xT);
    tabl_mfma<<<dim3(1024), 512, 0, stream>>>(xT, W1h, WT, W2T, alpha, bias, out);
    softmax_o1<<<B_, 256, 0, stream>>>(out);
}